// Round 1
// baseline (2640.985 us; speedup 1.0000x reference)
//
#include <hip/hip_runtime.h>

#define EPS 1e-5f

// ---------------- scatter-add (segment_sum of feat[src] into agg[dst]) ----------------
__global__ __launch_bounds__(256) void scatter_kernel(
    const float* __restrict__ feat, float* __restrict__ agg,
    const int* __restrict__ ei, int E)
{
    int gid = blockIdx.x * 256 + threadIdx.x;
    int e = gid >> 5;              // 32 threads per edge
    if (e >= E) return;
    int c4 = gid & 31;             // float4 slot within the 128-wide row
    int s = ei[e];                 // edge_index[0][e] = src
    int d = ei[E + e];             // edge_index[1][e] = dst
    float4 v = *(const float4*)(feat + (size_t)s * 128 + c4 * 4);
    float* p = agg + (size_t)d * 128 + c4 * 4;
    atomicAdd(p + 0, v.x);
    atomicAdd(p + 1, v.y);
    atomicAdd(p + 2, v.z);
    atomicAdd(p + 3, v.w);
}

// ---------------- fused linear: Y = Xa@Wa (+ Xb@Wb) + bias, optional ReLU ----------------
// Block: 256 threads -> 128 rows x 128 cols tile. Thread (tr,tc): 8 rows x 8 cols, 64 acc.
// K staged in LDS chunks of 32, layout [k][row] (129-pad => conflict-free reads).
// Weights read from global (16KB/chunk -> L1-hot, broadcast across thread-rows).
// In-place safe (Y == Xa): all reads of a block's rows complete before epilogue stores.
template<int DUAL, int RELU>
__global__ __launch_bounds__(256) void lin_kernel(
    const float* __restrict__ Xa, const float* __restrict__ Xb,
    const float* __restrict__ Wa, const float* __restrict__ Wb,
    const float* __restrict__ bias, float* __restrict__ Y, int nrows)
{
    __shared__ float sA[32][129];
    __shared__ float sB[DUAL ? 32 : 1][129];
    const int tid = threadIdx.x;
    const int tr = tid >> 4;   // 0..15, owns rows tr*8..tr*8+7
    const int tc = tid & 15;   // 0..15, owns cols tc*8..tc*8+7
    const int row0 = blockIdx.x * 128;

    float acc[8][8];
#pragma unroll
    for (int i = 0; i < 8; ++i)
#pragma unroll
        for (int j = 0; j < 8; ++j) acc[i][j] = 0.f;

    for (int kb = 0; kb < 4; ++kb) {
        __syncthreads();
        // stage 128 rows x 32 k
#pragma unroll
        for (int i = 0; i < 4; ++i) {
            int id = tid + i * 256;   // 0..1023 float4 units
            int r = id >> 3;          // 0..127
            int k4 = id & 7;          // 0..7
            int gr = row0 + r;
            float4 va = make_float4(0.f, 0.f, 0.f, 0.f);
            if (gr < nrows) va = *(const float4*)(Xa + (size_t)gr * 128 + kb * 32 + k4 * 4);
            sA[k4 * 4 + 0][r] = va.x;
            sA[k4 * 4 + 1][r] = va.y;
            sA[k4 * 4 + 2][r] = va.z;
            sA[k4 * 4 + 3][r] = va.w;
            if (DUAL) {
                float4 vb = make_float4(0.f, 0.f, 0.f, 0.f);
                if (gr < nrows) vb = *(const float4*)(Xb + (size_t)gr * 128 + kb * 32 + k4 * 4);
                sB[k4 * 4 + 0][r] = vb.x;
                sB[k4 * 4 + 1][r] = vb.y;
                sB[k4 * 4 + 2][r] = vb.z;
                sB[k4 * 4 + 3][r] = vb.w;
            }
        }
        __syncthreads();
#pragma unroll 4
        for (int kk = 0; kk < 32; ++kk) {
            const int k = kb * 32 + kk;
            float4 wa0 = *(const float4*)(Wa + (size_t)k * 128 + tc * 8);
            float4 wa1 = *(const float4*)(Wa + (size_t)k * 128 + tc * 8 + 4);
            float a[8];
#pragma unroll
            for (int i = 0; i < 8; ++i) a[i] = sA[kk][tr * 8 + i];
#pragma unroll
            for (int i = 0; i < 8; ++i) {
                acc[i][0] += a[i] * wa0.x; acc[i][1] += a[i] * wa0.y;
                acc[i][2] += a[i] * wa0.z; acc[i][3] += a[i] * wa0.w;
                acc[i][4] += a[i] * wa1.x; acc[i][5] += a[i] * wa1.y;
                acc[i][6] += a[i] * wa1.z; acc[i][7] += a[i] * wa1.w;
            }
            if (DUAL) {
                float4 wb0 = *(const float4*)(Wb + (size_t)k * 128 + tc * 8);
                float4 wb1 = *(const float4*)(Wb + (size_t)k * 128 + tc * 8 + 4);
                float b[8];
#pragma unroll
                for (int i = 0; i < 8; ++i) b[i] = sB[kk][tr * 8 + i];
#pragma unroll
                for (int i = 0; i < 8; ++i) {
                    acc[i][0] += b[i] * wb0.x; acc[i][1] += b[i] * wb0.y;
                    acc[i][2] += b[i] * wb0.z; acc[i][3] += b[i] * wb0.w;
                    acc[i][4] += b[i] * wb1.x; acc[i][5] += b[i] * wb1.y;
                    acc[i][6] += b[i] * wb1.z; acc[i][7] += b[i] * wb1.w;
                }
            }
        }
    }

    float4 bi0 = *(const float4*)(bias + tc * 8);
    float4 bi1 = *(const float4*)(bias + tc * 8 + 4);
#pragma unroll
    for (int i = 0; i < 8; ++i) {
        int gr = row0 + tr * 8 + i;
        if (gr < nrows) {
            float y[8];
            y[0] = acc[i][0] + bi0.x; y[1] = acc[i][1] + bi0.y;
            y[2] = acc[i][2] + bi0.z; y[3] = acc[i][3] + bi0.w;
            y[4] = acc[i][4] + bi1.x; y[5] = acc[i][5] + bi1.y;
            y[6] = acc[i][6] + bi1.z; y[7] = acc[i][7] + bi1.w;
            if (RELU) {
#pragma unroll
                for (int j = 0; j < 8; ++j) y[j] = fmaxf(y[j], 0.f);
            }
            *(float4*)(Y + (size_t)gr * 128 + tc * 8)     = make_float4(y[0], y[1], y[2], y[3]);
            *(float4*)(Y + (size_t)gr * 128 + tc * 8 + 4) = make_float4(y[4], y[5], y[6], y[7]);
        }
    }
}

// ---------------- per-column sum / sumsq ----------------
__global__ __launch_bounds__(256) void stats_kernel(
    const float* __restrict__ H, float* __restrict__ st, int nrows)
{
    int col = threadIdx.x & 127;
    int rh = threadIdx.x >> 7;   // 0..1
    float s = 0.f, q = 0.f;
    for (int r = blockIdx.x * 2 + rh; r < nrows; r += gridDim.x * 2) {
        float v = H[(size_t)r * 128 + col];
        s += v; q += v * v;
    }
    __shared__ float red[2][2][128];
    red[0][rh][col] = s;
    red[1][rh][col] = q;
    __syncthreads();
    if (rh == 0) {
        atomicAdd(&st[col],       s + red[0][1][col]);
        atomicAdd(&st[128 + col], q + red[1][1][col]);
    }
}

__global__ void finalize_kernel(float* st, float inv_n) {
    int c = threadIdx.x;
    float mu = st[c] * inv_n;
    float var = st[128 + c] * inv_n - mu * mu;
    st[256 + c] = mu;
    st[384 + c] = rsqrtf(var + EPS);
}

// ---------------- BN normalize + ReLU (in place) ----------------
__global__ __launch_bounds__(256) void bnrelu_kernel(
    float* __restrict__ H, const float* __restrict__ st,
    const float* __restrict__ gamma, const float* __restrict__ beta, int n4)
{
    for (int i = blockIdx.x * 256 + threadIdx.x; i < n4; i += gridDim.x * 256) {
        int c4 = i & 31;
        float4 h = ((float4*)H)[i];
        float4 mu = *(const float4*)(st + 256 + c4 * 4);
        float4 rs = *(const float4*)(st + 384 + c4 * 4);
        float4 g  = *(const float4*)(gamma + c4 * 4);
        float4 b  = *(const float4*)(beta + c4 * 4);
        h.x = fmaxf((h.x - mu.x) * rs.x * g.x + b.x, 0.f);
        h.y = fmaxf((h.y - mu.y) * rs.y * g.y + b.y, 0.f);
        h.z = fmaxf((h.z - mu.z) * rs.z * g.z + b.z, 0.f);
        h.w = fmaxf((h.w - mu.w) * rs.w * g.w + b.w, 0.f);
        ((float4*)H)[i] = h;
    }
}

// ---------------- final projection to DOUT=2 ----------------
__global__ __launch_bounds__(256) void linout_kernel(
    const float* __restrict__ X, const float* __restrict__ W, const float* __restrict__ b,
    float* __restrict__ out, int nrows)
{
    int r = blockIdx.x * 256 + threadIdx.x;
    if (r >= nrows) return;
    float a0 = 0.f, a1 = 0.f;
    const float* xr = X + (size_t)r * 128;
#pragma unroll 8
    for (int k = 0; k < 128; k += 4) {
        float4 x = *(const float4*)(xr + k);
        a0 += x.x * W[(k + 0) * 2]     + x.y * W[(k + 1) * 2]
            + x.z * W[(k + 2) * 2]     + x.w * W[(k + 3) * 2];
        a1 += x.x * W[(k + 0) * 2 + 1] + x.y * W[(k + 1) * 2 + 1]
            + x.z * W[(k + 2) * 2 + 1] + x.w * W[(k + 3) * 2 + 1];
    }
    float2 o = make_float2(a0 + b[0], a1 + b[1]);
    *(float2*)(out + (size_t)r * 2) = o;
}

extern "C" void kernel_launch(void* const* d_in, const int* in_sizes, int n_in,
                              void* d_out, int out_size, void* d_ws, size_t ws_size,
                              hipStream_t stream) {
    const float* x   = (const float*)d_in[0];
    const int*   ei  = (const int*)d_in[1];
    const float* Wl0 = (const float*)d_in[2];
    const float* bl0 = (const float*)d_in[3];
    const float* Wr0 = (const float*)d_in[4];
    const float* Wl1 = (const float*)d_in[5];
    const float* bl1 = (const float*)d_in[6];
    const float* Wr1 = (const float*)d_in[7];
    const float* g0  = (const float*)d_in[8];
    const float* be0 = (const float*)d_in[9];
    const float* g1  = (const float*)d_in[10];
    const float* be1 = (const float*)d_in[11];
    const float* W1  = (const float*)d_in[12];
    const float* b1  = (const float*)d_in[13];
    const float* W2  = (const float*)d_in[14];
    const float* b2  = (const float*)d_in[15];
    const float* W3  = (const float*)d_in[16];
    const float* b3  = (const float*)d_in[17];
    float* out = (float*)d_out;

    const int N = in_sizes[0] / 128;
    const int E = in_sizes[1] / 2;

    float* A  = (float*)d_ws;                 // [N,128]
    float* B  = A + (size_t)N * 128;          // [N,128]
    float* st = B + (size_t)N * 128;          // sum[128], sumsq[128], mu[128], rsig[128]

    const size_t featBytes = (size_t)N * 128 * sizeof(float);
    const int linGrid  = (N + 127) / 128;
    const int scatGrid = (E * 32 + 255) / 256;
    const float inv_n = 1.0f / (float)N;

    // ----- layer 0: h0 = bn_relu(agg(x)@Wl0 + x@Wr0 + bl0) -----
    hipMemsetAsync(A, 0, featBytes, stream);
    scatter_kernel<<<scatGrid, 256, 0, stream>>>(x, A, ei, E);
    lin_kernel<1, 0><<<linGrid, 256, 0, stream>>>(A, x, Wl0, Wr0, bl0, A, N);
    hipMemsetAsync(st, 0, 256 * sizeof(float), stream);
    stats_kernel<<<512, 256, 0, stream>>>(A, st, N);
    finalize_kernel<<<1, 128, 0, stream>>>(st, inv_n);
    bnrelu_kernel<<<2048, 256, 0, stream>>>(A, st, g0, be0, N * 32);

    // ----- layer 1: h1 = bn_relu(agg(h0)@Wl1 + h0@Wr1 + bl1) -----
    hipMemsetAsync(B, 0, featBytes, stream);
    scatter_kernel<<<scatGrid, 256, 0, stream>>>(A, B, ei, E);
    lin_kernel<1, 0><<<linGrid, 256, 0, stream>>>(B, A, Wl1, Wr1, bl1, B, N);
    hipMemsetAsync(st, 0, 256 * sizeof(float), stream);
    stats_kernel<<<512, 256, 0, stream>>>(B, st, N);
    finalize_kernel<<<1, 128, 0, stream>>>(st, inv_n);
    bnrelu_kernel<<<2048, 256, 0, stream>>>(B, st, g1, be1, N * 32);

    // ----- MLP head -----
    lin_kernel<0, 1><<<linGrid, 256, 0, stream>>>(B, nullptr, W1, nullptr, b1, A, N);
    lin_kernel<0, 1><<<linGrid, 256, 0, stream>>>(A, nullptr, W2, nullptr, b2, B, N);
    linout_kernel<<<(N + 255) / 256, 256, 0, stream>>>(B, W3, b3, out, N);
}

// Round 2
// 771.399 us; speedup vs baseline: 3.4236x; 3.4236x over previous
//
#include <hip/hip_runtime.h>

#define EPS 1e-5f

// ================= CSR build =================
__global__ __launch_bounds__(256) void hist_kernel(
    const int* __restrict__ ei, int* __restrict__ deg, int E)
{
    int e = blockIdx.x * 256 + threadIdx.x;
    if (e >= E) return;
    atomicAdd(&deg[ei[E + e]], 1);
}

__global__ __launch_bounds__(256) void blocksum_kernel(
    const int* __restrict__ deg, int* __restrict__ bsum, int N)
{
    int i = blockIdx.x * 256 + threadIdx.x;
    int v = (i < N) ? deg[i] : 0;
#pragma unroll
    for (int o = 1; o < 64; o <<= 1) v += __shfl_xor(v, o);
    __shared__ int s[4];
    if ((threadIdx.x & 63) == 0) s[threadIdx.x >> 6] = v;
    __syncthreads();
    if (threadIdx.x == 0) bsum[blockIdx.x] = s[0] + s[1] + s[2] + s[3];
}

// single block, exclusive scan of bsum[0..NB), NB <= 512
__global__ __launch_bounds__(512) void scanb_kernel(int* bsum, int NB)
{
    __shared__ int sh[512];
    int t = threadIdx.x;
    int v = (t < NB) ? bsum[t] : 0;
    sh[t] = v;
    __syncthreads();
    for (int o = 1; o < 512; o <<= 1) {
        int add = (t >= o) ? sh[t - o] : 0;
        __syncthreads();
        sh[t] += add;
        __syncthreads();
    }
    if (t < NB) bsum[t] = (t == 0) ? 0 : sh[t - 1];
}

__global__ __launch_bounds__(256) void scanfinal_kernel(
    const int* __restrict__ deg, const int* __restrict__ bsum,
    int* __restrict__ rowptr, int* __restrict__ cursor, int N)
{
    int b = blockIdx.x, t = threadIdx.x;
    int i = b * 256 + t;
    int v = (i < N) ? deg[i] : 0;
    __shared__ int sh[256];
    sh[t] = v;
    __syncthreads();
    for (int o = 1; o < 256; o <<= 1) {
        int add = (t >= o) ? sh[t - o] : 0;
        __syncthreads();
        sh[t] += add;
        __syncthreads();
    }
    int excl = sh[t] - v;
    if (i < N) {
        int rp = bsum[b] + excl;
        rowptr[i] = rp;
        cursor[i] = rp;
        if (i == N - 1) rowptr[N] = rp + v;
    }
}

__global__ __launch_bounds__(256) void fill_kernel(
    const int* __restrict__ ei, int* __restrict__ cursor, int* __restrict__ col, int E)
{
    int e = blockIdx.x * 256 + threadIdx.x;
    if (e >= E) return;
    int d = ei[E + e];
    int pos = atomicAdd(&cursor[d], 1);
    col[pos] = ei[e];
}

// ================= CSR gather: agg[n] = sum_{e in row n} feat[col[e]] =================
// 32 lanes per node (float4 each), 2-edge unroll for load ILP.
__global__ __launch_bounds__(256) void gather_kernel(
    const float* __restrict__ feat, float* __restrict__ agg,
    const int* __restrict__ rowptr, const int* __restrict__ col, int N)
{
    int gid = blockIdx.x * 256 + threadIdx.x;
    int n = gid >> 5;
    if (n >= N) return;
    int l = gid & 31;
    int beg = rowptr[n], end = rowptr[n + 1];
    float a0x = 0.f, a0y = 0.f, a0z = 0.f, a0w = 0.f;
    float a1x = 0.f, a1y = 0.f, a1z = 0.f, a1w = 0.f;
    int e = beg;
    for (; e + 2 <= end; e += 2) {
        int s0 = col[e], s1 = col[e + 1];
        float4 v0 = *(const float4*)(feat + (size_t)s0 * 128 + l * 4);
        float4 v1 = *(const float4*)(feat + (size_t)s1 * 128 + l * 4);
        a0x += v0.x; a0y += v0.y; a0z += v0.z; a0w += v0.w;
        a1x += v1.x; a1y += v1.y; a1z += v1.z; a1w += v1.w;
    }
    if (e < end) {
        int s0 = col[e];
        float4 v0 = *(const float4*)(feat + (size_t)s0 * 128 + l * 4);
        a0x += v0.x; a0y += v0.y; a0z += v0.z; a0w += v0.w;
    }
    *(float4*)(agg + (size_t)n * 128 + l * 4) =
        make_float4(a0x + a1x, a0y + a1y, a0z + a1z, a0w + a1w);
}

// ================= fused linear: Y = Xa@Wa (+ Xb@Wb) + bias, optional ReLU =================
template<int DUAL, int RELU>
__global__ __launch_bounds__(256) void lin_kernel(
    const float* __restrict__ Xa, const float* __restrict__ Xb,
    const float* __restrict__ Wa, const float* __restrict__ Wb,
    const float* __restrict__ bias, float* __restrict__ Y, int nrows)
{
    __shared__ float sA[32][129];
    __shared__ float sB[DUAL ? 32 : 1][129];
    const int tid = threadIdx.x;
    const int tr = tid >> 4;
    const int tc = tid & 15;
    const int row0 = blockIdx.x * 128;

    float acc[8][8];
#pragma unroll
    for (int i = 0; i < 8; ++i)
#pragma unroll
        for (int j = 0; j < 8; ++j) acc[i][j] = 0.f;

    for (int kb = 0; kb < 4; ++kb) {
        __syncthreads();
#pragma unroll
        for (int i = 0; i < 4; ++i) {
            int id = tid + i * 256;
            int r = id >> 3;
            int k4 = id & 7;
            int gr = row0 + r;
            float4 va = make_float4(0.f, 0.f, 0.f, 0.f);
            if (gr < nrows) va = *(const float4*)(Xa + (size_t)gr * 128 + kb * 32 + k4 * 4);
            sA[k4 * 4 + 0][r] = va.x;
            sA[k4 * 4 + 1][r] = va.y;
            sA[k4 * 4 + 2][r] = va.z;
            sA[k4 * 4 + 3][r] = va.w;
            if (DUAL) {
                float4 vb = make_float4(0.f, 0.f, 0.f, 0.f);
                if (gr < nrows) vb = *(const float4*)(Xb + (size_t)gr * 128 + kb * 32 + k4 * 4);
                sB[k4 * 4 + 0][r] = vb.x;
                sB[k4 * 4 + 1][r] = vb.y;
                sB[k4 * 4 + 2][r] = vb.z;
                sB[k4 * 4 + 3][r] = vb.w;
            }
        }
        __syncthreads();
#pragma unroll 4
        for (int kk = 0; kk < 32; ++kk) {
            const int k = kb * 32 + kk;
            float4 wa0 = *(const float4*)(Wa + (size_t)k * 128 + tc * 8);
            float4 wa1 = *(const float4*)(Wa + (size_t)k * 128 + tc * 8 + 4);
            float a[8];
#pragma unroll
            for (int i = 0; i < 8; ++i) a[i] = sA[kk][tr * 8 + i];
#pragma unroll
            for (int i = 0; i < 8; ++i) {
                acc[i][0] += a[i] * wa0.x; acc[i][1] += a[i] * wa0.y;
                acc[i][2] += a[i] * wa0.z; acc[i][3] += a[i] * wa0.w;
                acc[i][4] += a[i] * wa1.x; acc[i][5] += a[i] * wa1.y;
                acc[i][6] += a[i] * wa1.z; acc[i][7] += a[i] * wa1.w;
            }
            if (DUAL) {
                float4 wb0 = *(const float4*)(Wb + (size_t)k * 128 + tc * 8);
                float4 wb1 = *(const float4*)(Wb + (size_t)k * 128 + tc * 8 + 4);
                float b[8];
#pragma unroll
                for (int i = 0; i < 8; ++i) b[i] = sB[kk][tr * 8 + i];
#pragma unroll
                for (int i = 0; i < 8; ++i) {
                    acc[i][0] += b[i] * wb0.x; acc[i][1] += b[i] * wb0.y;
                    acc[i][2] += b[i] * wb0.z; acc[i][3] += b[i] * wb0.w;
                    acc[i][4] += b[i] * wb1.x; acc[i][5] += b[i] * wb1.y;
                    acc[i][6] += b[i] * wb1.z; acc[i][7] += b[i] * wb1.w;
                }
            }
        }
    }

    float4 bi0 = *(const float4*)(bias + tc * 8);
    float4 bi1 = *(const float4*)(bias + tc * 8 + 4);
#pragma unroll
    for (int i = 0; i < 8; ++i) {
        int gr = row0 + tr * 8 + i;
        if (gr < nrows) {
            float y[8];
            y[0] = acc[i][0] + bi0.x; y[1] = acc[i][1] + bi0.y;
            y[2] = acc[i][2] + bi0.z; y[3] = acc[i][3] + bi0.w;
            y[4] = acc[i][4] + bi1.x; y[5] = acc[i][5] + bi1.y;
            y[6] = acc[i][6] + bi1.z; y[7] = acc[i][7] + bi1.w;
            if (RELU) {
#pragma unroll
                for (int j = 0; j < 8; ++j) y[j] = fmaxf(y[j], 0.f);
            }
            *(float4*)(Y + (size_t)gr * 128 + tc * 8)     = make_float4(y[0], y[1], y[2], y[3]);
            *(float4*)(Y + (size_t)gr * 128 + tc * 8 + 4) = make_float4(y[4], y[5], y[6], y[7]);
        }
    }
}

// ================= per-column sum / sumsq =================
__global__ __launch_bounds__(256) void stats_kernel(
    const float* __restrict__ H, float* __restrict__ st, int nrows)
{
    int col = threadIdx.x & 127;
    int rh = threadIdx.x >> 7;
    float s = 0.f, q = 0.f;
    for (int r = blockIdx.x * 2 + rh; r < nrows; r += gridDim.x * 2) {
        float v = H[(size_t)r * 128 + col];
        s += v; q += v * v;
    }
    __shared__ float red[2][2][128];
    red[0][rh][col] = s;
    red[1][rh][col] = q;
    __syncthreads();
    if (rh == 0) {
        atomicAdd(&st[col],       s + red[0][1][col]);
        atomicAdd(&st[128 + col], q + red[1][1][col]);
    }
}

__global__ void finalize_kernel(float* st, float inv_n) {
    int c = threadIdx.x;
    float mu = st[c] * inv_n;
    float var = st[128 + c] * inv_n - mu * mu;
    st[256 + c] = mu;
    st[384 + c] = rsqrtf(var + EPS);
}

// ================= BN normalize + ReLU (in place) =================
__global__ __launch_bounds__(256) void bnrelu_kernel(
    float* __restrict__ H, const float* __restrict__ st,
    const float* __restrict__ gamma, const float* __restrict__ beta, int n4)
{
    for (int i = blockIdx.x * 256 + threadIdx.x; i < n4; i += gridDim.x * 256) {
        int c4 = i & 31;
        float4 h = ((float4*)H)[i];
        float4 mu = *(const float4*)(st + 256 + c4 * 4);
        float4 rs = *(const float4*)(st + 384 + c4 * 4);
        float4 g  = *(const float4*)(gamma + c4 * 4);
        float4 b  = *(const float4*)(beta + c4 * 4);
        h.x = fmaxf((h.x - mu.x) * rs.x * g.x + b.x, 0.f);
        h.y = fmaxf((h.y - mu.y) * rs.y * g.y + b.y, 0.f);
        h.z = fmaxf((h.z - mu.z) * rs.z * g.z + b.z, 0.f);
        h.w = fmaxf((h.w - mu.w) * rs.w * g.w + b.w, 0.f);
        ((float4*)H)[i] = h;
    }
}

// ================= final projection to DOUT=2 =================
__global__ __launch_bounds__(256) void linout_kernel(
    const float* __restrict__ X, const float* __restrict__ W, const float* __restrict__ b,
    float* __restrict__ out, int nrows)
{
    int r = blockIdx.x * 256 + threadIdx.x;
    if (r >= nrows) return;
    float a0 = 0.f, a1 = 0.f;
    const float* xr = X + (size_t)r * 128;
#pragma unroll 8
    for (int k = 0; k < 128; k += 4) {
        float4 x = *(const float4*)(xr + k);
        a0 += x.x * W[(k + 0) * 2]     + x.y * W[(k + 1) * 2]
            + x.z * W[(k + 2) * 2]     + x.w * W[(k + 3) * 2];
        a1 += x.x * W[(k + 0) * 2 + 1] + x.y * W[(k + 1) * 2 + 1]
            + x.z * W[(k + 2) * 2 + 1] + x.w * W[(k + 3) * 2 + 1];
    }
    float2 o = make_float2(a0 + b[0], a1 + b[1]);
    *(float2*)(out + (size_t)r * 2) = o;
}

extern "C" void kernel_launch(void* const* d_in, const int* in_sizes, int n_in,
                              void* d_out, int out_size, void* d_ws, size_t ws_size,
                              hipStream_t stream) {
    const float* x   = (const float*)d_in[0];
    const int*   ei  = (const int*)d_in[1];
    const float* Wl0 = (const float*)d_in[2];
    const float* bl0 = (const float*)d_in[3];
    const float* Wr0 = (const float*)d_in[4];
    const float* Wl1 = (const float*)d_in[5];
    const float* bl1 = (const float*)d_in[6];
    const float* Wr1 = (const float*)d_in[7];
    const float* g0  = (const float*)d_in[8];
    const float* be0 = (const float*)d_in[9];
    const float* g1  = (const float*)d_in[10];
    const float* be1 = (const float*)d_in[11];
    const float* W1  = (const float*)d_in[12];
    const float* b1  = (const float*)d_in[13];
    const float* W2  = (const float*)d_in[14];
    const float* b2  = (const float*)d_in[15];
    const float* W3  = (const float*)d_in[16];
    const float* b3  = (const float*)d_in[17];
    float* out = (float*)d_out;

    const int N = in_sizes[0] / 128;
    const int E = in_sizes[1] / 2;

    // workspace layout
    float* A  = (float*)d_ws;                  // [N,128]
    float* B  = A + (size_t)N * 128;           // [N,128]
    float* st = B + (size_t)N * 128;           // 512 floats
    int* deg    = (int*)(st + 512);            // N
    int* rowptr = deg + N;                     // N+1
    int* cursor = rowptr + N + 1;              // N
    int* col    = cursor + N;                  // E
    int* bsum   = col + E;                     // <=512

    const int linGrid    = (N + 127) / 128;
    const int edgeGrid   = (E + 255) / 256;
    const int nodeGrid   = (N + 255) / 256;    // also NB for scan
    const int gatherGrid = ((size_t)N * 32 + 255) / 256;
    const float inv_n = 1.0f / (float)N;

    // ----- CSR build (once, reused by both layers) -----
    hipMemsetAsync(deg, 0, (size_t)N * sizeof(int), stream);
    hist_kernel<<<edgeGrid, 256, 0, stream>>>(ei, deg, E);
    blocksum_kernel<<<nodeGrid, 256, 0, stream>>>(deg, bsum, N);
    scanb_kernel<<<1, 512, 0, stream>>>(bsum, nodeGrid);
    scanfinal_kernel<<<nodeGrid, 256, 0, stream>>>(deg, bsum, rowptr, cursor, N);
    fill_kernel<<<edgeGrid, 256, 0, stream>>>(ei, cursor, col, E);

    // ----- layer 0 -----
    gather_kernel<<<gatherGrid, 256, 0, stream>>>(x, A, rowptr, col, N);
    lin_kernel<1, 0><<<linGrid, 256, 0, stream>>>(A, x, Wl0, Wr0, bl0, A, N);
    hipMemsetAsync(st, 0, 256 * sizeof(float), stream);
    stats_kernel<<<512, 256, 0, stream>>>(A, st, N);
    finalize_kernel<<<1, 128, 0, stream>>>(st, inv_n);
    bnrelu_kernel<<<2048, 256, 0, stream>>>(A, st, g0, be0, N * 32);

    // ----- layer 1 -----
    gather_kernel<<<gatherGrid, 256, 0, stream>>>(A, B, rowptr, col, N);
    lin_kernel<1, 0><<<linGrid, 256, 0, stream>>>(B, A, Wl1, Wr1, bl1, B, N);
    hipMemsetAsync(st, 0, 256 * sizeof(float), stream);
    stats_kernel<<<512, 256, 0, stream>>>(B, st, N);
    finalize_kernel<<<1, 128, 0, stream>>>(st, inv_n);
    bnrelu_kernel<<<2048, 256, 0, stream>>>(B, st, g1, be1, N * 32);

    // ----- MLP head -----
    lin_kernel<0, 1><<<linGrid, 256, 0, stream>>>(B, nullptr, W1, nullptr, b1, A, N);
    lin_kernel<0, 1><<<linGrid, 256, 0, stream>>>(A, nullptr, W2, nullptr, b2, B, N);
    linout_kernel<<<(N + 255) / 256, 256, 0, stream>>>(B, W3, b3, out, N);
}